// Round 19
// baseline (158.156 us; speedup 1.0000x reference)
//
#include <hip/hip_runtime.h>

// DigiCaps dynamic routing — R18 base, conv kernel folded into staging.
// inputs [512,1152,8] f32, W [10,1152,16,8] f32, out v [512,10,16] f32.
// u_hat[b,j,i,d] = sum_k x[b,i,k] W[j,i,d,k]; logits b_t = u_hat . vsum
// (vsum = running sum of v's) -> u_hat never materialized.
//
// R18: 156.3us best (fp16-packed butterfly -2.5us/pass). Passes remain
// latency-plateaued at ~42us vs ~15us pipe budget across 12 structural
// variants — all pipes <25%. R19: the last clean structural cut — delete
// the standalone f32->bf16 conv kernel; each pass stages straight from the
// f32 inputs and converts inline (R11-producer-validated pattern, same RNE
// f2bf -> bit-identical results). Saves ~10us conv + a launch gap.
// MFMA f32_16x16x32_bf16, C-layout: lane&15=b(col), (lane>>4)*4+reg=d(row);
// A-frags K=32-packed (lane (kg,bl) = W[i4+kg, j, d=bl]); MODE0 contracts
// 4 i's per MFMA exactly; MODE1 isolates i=q by masking B (kg==q ? xv : 0),
// fp16x2 logit butterfly (10 shfl + 10 pk_add), no max-subtract (|logit|
// bounded ~3). absmax ~4e-3 (threshold 17.5e-3).

#define NB 512
#define NI 1152
#define NJ 10
#define ND 16

typedef short          bf16x8 __attribute__((ext_vector_type(8)));
typedef unsigned short u16x8  __attribute__((ext_vector_type(8)));
typedef float          f32x4  __attribute__((ext_vector_type(4)));
typedef __fp16         h16x2  __attribute__((ext_vector_type(2)));

constexpr float EPS_ = 1e-7f;
constexpr int   NIGB = 144;   // i-groups of 8

__device__ inline unsigned short f2bf(float f) {   // RNE f32->bf16
    unsigned u = __float_as_uint(f);
    return (unsigned short)((u + 0x7fffu + ((u >> 16) & 1u)) >> 16);
}
__device__ inline float bf2f(unsigned short u) {
    return __uint_as_float((unsigned)u << 16);
}
__device__ inline u16x8 cvt8(const float4& a, const float4& c) {
    u16x8 o;
    o[0] = f2bf(a.x); o[1] = f2bf(a.y); o[2] = f2bf(a.z); o[3] = f2bf(a.w);
    o[4] = f2bf(c.x); o[5] = f2bf(c.y); o[6] = f2bf(c.z); o[7] = f2bf(c.w);
    return o;
}

// Block: 64 b (4 waves x 16) x 8 i (two 4-i K-packs). LDS ~30KB.
template <int MODE>
__global__ __launch_bounds__(256, 2)
void caps_pass(const float* __restrict__ xf,
               const float* __restrict__ Wf,
               const float* __restrict__ vsum_g,
               unsigned short* __restrict__ part)
{
    // wl: granule g = il*161 + j*16 + d (pad granule breaks kg-group
    // aliasing). xl: row stride 9 granules. Epilogue reuses smem as
    // bf16 s16[64][168].
    __shared__ __align__(16) char smem[30368];
    unsigned short* wl = (unsigned short*)smem;                 // 1288 granules
    unsigned short* xl = (unsigned short*)(smem + 20608);       // 576 granules

    const int tid = threadIdx.x, lane = tid & 63, w = tid >> 6;
    const int bl = lane & 15, kg = lane >> 4;
    const int bg = blockIdx.x, ig = blockIdx.y;
    const int i0 = ig * 8, b0 = bg * 64;
    const int b  = b0 + w * 16 + bl;
    const int brow = w * 16 + bl;

    // stage W (inline f32->bf16): 1280 granules -> slot il*161 + rem
#pragma unroll
    for (int r = 0; r < 5; ++r) {
        int g  = tid + r * 256;
        int il = g / 160, rem = g - il * 160;
        const float4* s = (const float4*)(
            Wf + (((size_t)(rem >> 4) * NI + (i0 + il)) * 16 + (rem & 15)) * 8);
        float4 a = s[0], c = s[1];
        *(u16x8*)(wl + (il * 161 + rem) * 8) = cvt8(a, c);
    }
    // stage x (inline f32->bf16): slot brow*9 + il <- x[b0+br, i0+il, 0:8]
#pragma unroll
    for (int r = 0; r < 2; ++r) {
        int g = tid + r * 256;
        if (g < 512) {
            int br = g >> 3, il = g & 7;
            const float4* s = (const float4*)(
                xf + ((size_t)(b0 + br) * NI + i0 + il) * 8);
            float4 a = s[0], c = s[1];
            *(u16x8*)(xl + (br * 9 + il) * 8) = cvt8(a, c);
        }
    }

    f32x4 vs[NJ];
    if (MODE == 1) {
#pragma unroll
        for (int j = 0; j < NJ; ++j)
            vs[j] = *(const f32x4*)(vsum_g + (size_t)b * 160 + j * 16 + kg * 4);
    }

    __syncthreads();

    const f32x4  zero  = {0.f, 0.f, 0.f, 0.f};
    const bf16x8 zerob = {0, 0, 0, 0, 0, 0, 0, 0};
    f32x4 sacc[NJ];
#pragma unroll
    for (int j = 0; j < NJ; ++j) sacc[j] = zero;

#pragma unroll
    for (int t4 = 0; t4 < 2; ++t4) {
        // A-frags: lane (kg,bl) = W[i0+t4*4+kg, j, d=bl, 0:8] — K=32 packed,
        // all 64 lanes real; 10 reads per FOUR i's.
        bf16x8 afull[NJ];
#pragma unroll
        for (int j = 0; j < NJ; ++j)
            afull[j] = *(const bf16x8*)(wl + (((t4 * 4 + kg) * 161) + j * 16 + bl) * 8);
        bf16x8 xv = *(const bf16x8*)(xl + (brow * 9 + t4 * 4 + kg) * 8);

        if (MODE == 0) {
#pragma unroll
            for (int j = 0; j < NJ; ++j)
                sacc[j] = __builtin_amdgcn_mfma_f32_16x16x32_bf16(afull[j], xv, sacc[j], 0, 0, 0);
        } else {
#pragma unroll
            for (int q = 0; q < 4; ++q) {
                const bf16x8 bq = (kg == q) ? xv : zerob;   // isolate i = i0+t4*4+q
                f32x4 uh[NJ];
#pragma unroll
                for (int j = 0; j < NJ; ++j)
                    uh[j] = __builtin_amdgcn_mfma_f32_16x16x32_bf16(afull[j], bq, zero, 0, 0, 0);

                // per-lane partial dots over this lane's 4 d's (f32)
                float bd[NJ];
#pragma unroll
                for (int j = 0; j < NJ; ++j)
                    bd[j] = uh[j][0] * vs[j][0] + uh[j][1] * vs[j][1]
                          + uh[j][2] * vs[j][2] + uh[j][3] * vs[j][3];

                // fp16x2-packed butterfly over the 4 d-quad lane groups:
                // 10 shfl + 10 pk_add.
                h16x2 pk[5];
#pragma unroll
                for (int jp = 0; jp < 5; ++jp)
                    pk[jp] = __builtin_amdgcn_cvt_pkrtz(bd[2 * jp], bd[2 * jp + 1]);
#pragma unroll
                for (int jp = 0; jp < 5; ++jp) {
                    float f = __shfl_xor(__builtin_bit_cast(float, pk[jp]), 16, 64);
                    pk[jp] = pk[jp] + __builtin_bit_cast(h16x2, f);
                }
#pragma unroll
                for (int jp = 0; jp < 5; ++jp) {
                    float f = __shfl_xor(__builtin_bit_cast(float, pk[jp]), 32, 64);
                    pk[jp] = pk[jp] + __builtin_bit_cast(h16x2, f);
                }

                // softmax over j, no max-subtract (|logit| <= ~3, exp safe)
                float e[NJ];
#pragma unroll
                for (int jp = 0; jp < 5; ++jp) {
                    e[2 * jp]     = __expf((float)pk[jp][0]);
                    e[2 * jp + 1] = __expf((float)pk[jp][1]);
                }
                float Z = ((e[0] + e[1]) + (e[2] + e[3]))
                        + ((e[4] + e[5]) + (e[6] + e[7])) + (e[8] + e[9]);
                const float rZ = 1.f / Z;
#pragma unroll
                for (int j = 0; j < NJ; ++j) {
                    const float c = e[j] * rZ;
                    sacc[j] += c * uh[j];
                }
            }
        }
    }

    // epilogue: sacc -> bf16 LDS bounce -> dense contiguous bf16 partials
    __syncthreads();
    unsigned short* s16 = (unsigned short*)smem;   // [64][168]
#pragma unroll
    for (int j = 0; j < NJ; ++j) {
        ushort4 o;
        o.x = f2bf(sacc[j][0]); o.y = f2bf(sacc[j][1]);
        o.z = f2bf(sacc[j][2]); o.w = f2bf(sacc[j][3]);
        *(ushort4*)(s16 + brow * 168 + j * 16 + kg * 4) = o;
    }
    __syncthreads();
    unsigned short* pp = part + ((size_t)ig * NB + b0) * 160;
#pragma unroll
    for (int r = 0; r < 5; ++r) {
        int idx = tid + r * 256;                 // 1280 ushort8 chunks = 64x160
        int row = idx / 20, ch = idx - row * 20;
        *(u16x8*)(pp + idx * 8) = *(const u16x8*)(s16 + row * 168 + ch * 8);
    }
}

// Sum 144 bf16 ig-partials, scale, squash over d (16-lane shfl), update vsum/out.
__global__ __launch_bounds__(256)
void squash_reduce(const unsigned short* __restrict__ part,
                   float* __restrict__ vsum_g, float* __restrict__ out,
                   float alpha, int mode)
{
    const int t = blockIdx.x * 256 + threadIdx.x;   // < 81920 = b*160 + j*16 + d
    const unsigned short* p = part + t;
    float a0 = 0.f, a1 = 0.f, a2 = 0.f, a3 = 0.f;
#pragma unroll 4
    for (int ig = 0; ig < NIGB; ig += 4) {
        a0 += bf2f(p[(size_t)ig * 81920]);
        a1 += bf2f(p[(size_t)(ig + 1) * 81920]);
        a2 += bf2f(p[(size_t)(ig + 2) * 81920]);
        a3 += bf2f(p[(size_t)(ig + 3) * 81920]);
    }
    const float s = ((a0 + a1) + (a2 + a3)) * alpha;

    float sq = s * s;
    sq += __shfl_xor(sq, 1, 64);
    sq += __shfl_xor(sq, 2, 64);
    sq += __shfl_xor(sq, 4, 64);
    sq += __shfl_xor(sq, 8, 64);
    const float sc = sq / ((1.f + sq) * sqrtf(sq + EPS_));
    const float v  = sc * s;

    if (mode == 0)      vsum_g[t] = v;
    else if (mode == 1) vsum_g[t] += v;
    else                out[t] = v;
}

extern "C" void kernel_launch(void* const* d_in, const int* in_sizes, int n_in,
                              void* d_out, int out_size, void* d_ws, size_t ws_size,
                              hipStream_t stream)
{
    const float* inp = (const float*)d_in[0];
    const float* Wg  = (const float*)d_in[1];
    float* out = (float*)d_out;

    unsigned short* part = (unsigned short*)d_ws;             // [144][512][160] bf16
    float* vsum = (float*)(part + (size_t)NIGB * NB * 160);   // [512][10][16] f32

    dim3 grid(8, NIGB);   // (8,144) = 1152 blocks
    // iter 0: c uniform 1/10 (folded into alpha); K=32 contracts 4 i's exactly
    caps_pass<0><<<grid, 256, 0, stream>>>(inp, Wg, nullptr, part);
    squash_reduce<<<320, 256, 0, stream>>>(part, vsum, out, 0.1f, 0);
    // iter 1: logits = u_hat . v0
    caps_pass<1><<<grid, 256, 0, stream>>>(inp, Wg, vsum, part);
    squash_reduce<<<320, 256, 0, stream>>>(part, vsum, out, 1.0f, 1);
    // iter 2: logits = u_hat . (v0+v1)
    caps_pass<1><<<grid, 256, 0, stream>>>(inp, Wg, vsum, part);
    squash_reduce<<<320, 256, 0, stream>>>(part, vsum, out, 1.0f, 2);
}

// Round 20
// 155.340 us; speedup vs baseline: 1.0181x; 1.0181x over previous
//
#include <hip/hip_runtime.h>

// DigiCaps dynamic routing — FINAL: R18 (measured best, 156.3us).
// inputs [512,1152,8] f32, W [10,1152,16,8] f32, out v [512,10,16] f32.
// u_hat[b,j,i,d] = sum_k x[b,i,k] W[j,i,d,k]; logits b_t = u_hat . vsum
// (vsum = running sum of v's) -> u_hat never materialized (3 recompute
// passes; logit recurrence makes b-storage unnecessary).
//
// Session summary (518 -> 156 us):
//  - MFMA f32_16x16x32_bf16 for u_hat; C-layout lane&15=b, (lane>>4)*4+reg=d.
//  - A-frags K=32-packed: lane (kg,bl) = W[i4+kg, j, d=bl] (all lanes real);
//    MODE0 contracts 4 i's/MFMA exactly; MODE1 isolates i=q by masking B.
//  - bf16 tiles pre-converted once (standalone conv kernel; inlining it into
//    the passes regressed — R19).
//  - LDS staging via ordinary loads+ds_write ONLY: launch_bounds minimums
//    above 2 starve the allocator -> scratch spills masquerading as phantom
//    HBM traffic (R8-R10, R13). (256,2) = proven no-spill point.
//  - Epilogue: LDS bounce -> dense contiguous bf16 partials (partial-line
//    stores/atomics cost 15-30x line amplification — R8/R9).
//  - fp16x2-packed logit butterfly (10 shfl + 10 pk_add), no max-subtract.
//  - Cooperative grid.sync fusion costs ~100us/sync on 512 blocks — rejected.
// Plateau note: passes ~42us vs ~15us pipe budget, all pipes <25% busy —
// latency/issue-bound, not a pipe roofline; 13 structural variants bracket it.
// absmax 3.9e-3 (threshold 17.5e-3).

#define NB 512
#define NI 1152
#define NJ 10
#define ND 16

typedef short          bf16x8 __attribute__((ext_vector_type(8)));
typedef unsigned short u16x8  __attribute__((ext_vector_type(8)));
typedef float          f32x4  __attribute__((ext_vector_type(4)));
typedef __fp16         h16x2  __attribute__((ext_vector_type(2)));

constexpr float EPS_ = 1e-7f;

constexpr size_t XB_ELEMS = (size_t)NB * NI * 8;       // bf16
constexpr size_t WB_ELEMS = (size_t)NJ * NI * ND * 8;  // bf16
constexpr int    XQ = 1179648;                         // x float4 quads
constexpr int    WQ = 368640;                          // W float4 quads
constexpr int    NIGB = 144;                           // i-groups of 8

__device__ inline unsigned short f2bf(float f) {   // RNE f32->bf16
    unsigned u = __float_as_uint(f);
    return (unsigned short)((u + 0x7fffu + ((u >> 16) & 1u)) >> 16);
}
__device__ inline float bf2f(unsigned short u) {
    return __uint_as_float((unsigned)u << 16);
}

__global__ __launch_bounds__(256)
void conv_bf16(const float* __restrict__ x, const float* __restrict__ Wg,
               unsigned short* __restrict__ xb, unsigned short* __restrict__ wb)
{
    int t = blockIdx.x * 256 + threadIdx.x;
    if (t < XQ) {
        float4 v = ((const float4*)x)[t];
        ushort4 o; o.x=f2bf(v.x); o.y=f2bf(v.y); o.z=f2bf(v.z); o.w=f2bf(v.w);
        ((ushort4*)xb)[t] = o;
    } else if (t - XQ < WQ) {
        int u = t - XQ;
        float4 v = ((const float4*)Wg)[u];
        ushort4 o; o.x=f2bf(v.x); o.y=f2bf(v.y); o.z=f2bf(v.z); o.w=f2bf(v.w);
        ((ushort4*)wb)[u] = o;
    }
}

// Block: 64 b (4 waves x 16) x 8 i (two 4-i K-packs). LDS ~30KB.
template <int MODE>
__global__ __launch_bounds__(256, 2)
void caps_pass(const unsigned short* __restrict__ xb,
               const unsigned short* __restrict__ wb,
               const float* __restrict__ vsum_g,
               unsigned short* __restrict__ part)
{
    // wl: granule g = il*161 + j*16 + d (pad granule breaks kg-group
    // aliasing). xl: row stride 9 granules. Epilogue reuses smem as
    // bf16 s16[64][168].
    __shared__ __align__(16) char smem[30368];
    unsigned short* wl = (unsigned short*)smem;                 // 1288 granules
    unsigned short* xl = (unsigned short*)(smem + 20608);       // 576 granules

    const int tid = threadIdx.x, lane = tid & 63, w = tid >> 6;
    const int bl = lane & 15, kg = lane >> 4;
    const int bg = blockIdx.x, ig = blockIdx.y;
    const int i0 = ig * 8, b0 = bg * 64;
    const int b  = b0 + w * 16 + bl;
    const int brow = w * 16 + bl;

    // stage W: 1280 real granules -> slot il*161 + rem
#pragma unroll
    for (int r = 0; r < 5; ++r) {
        int g  = tid + r * 256;
        int il = g / 160, rem = g - il * 160;
        const unsigned short* src =
            wb + ((size_t)(rem >> 4) * NI + (i0 + il)) * 128 + (rem & 15) * 8;
        *(u16x8*)(wl + (il * 161 + rem) * 8) = *(const u16x8*)src;
    }
    // stage x: slot brow*9 + il  <-  x[b0+brow, i0+il, 0:8]
#pragma unroll
    for (int r = 0; r < 2; ++r) {
        int g = tid + r * 256;
        if (g < 512) {
            int br = g >> 3, il = g & 7;
            *(u16x8*)(xl + (br * 9 + il) * 8) =
                *(const u16x8*)(xb + ((size_t)(b0 + br) * NI + i0 + il) * 8);
        }
    }

    f32x4 vs[NJ];
    if (MODE == 1) {
#pragma unroll
        for (int j = 0; j < NJ; ++j)
            vs[j] = *(const f32x4*)(vsum_g + (size_t)b * 160 + j * 16 + kg * 4);
    }

    __syncthreads();

    const f32x4  zero  = {0.f, 0.f, 0.f, 0.f};
    const bf16x8 zerob = {0, 0, 0, 0, 0, 0, 0, 0};
    f32x4 sacc[NJ];
#pragma unroll
    for (int j = 0; j < NJ; ++j) sacc[j] = zero;

#pragma unroll
    for (int t4 = 0; t4 < 2; ++t4) {
        // A-frags: lane (kg,bl) = W[i0+t4*4+kg, j, d=bl, 0:8] — K=32 packed,
        // all 64 lanes real; 10 reads per FOUR i's.
        bf16x8 afull[NJ];
#pragma unroll
        for (int j = 0; j < NJ; ++j)
            afull[j] = *(const bf16x8*)(wl + (((t4 * 4 + kg) * 161) + j * 16 + bl) * 8);
        bf16x8 xv = *(const bf16x8*)(xl + (brow * 9 + t4 * 4 + kg) * 8);

        if (MODE == 0) {
#pragma unroll
            for (int j = 0; j < NJ; ++j)
                sacc[j] = __builtin_amdgcn_mfma_f32_16x16x32_bf16(afull[j], xv, sacc[j], 0, 0, 0);
        } else {
#pragma unroll
            for (int q = 0; q < 4; ++q) {
                const bf16x8 bq = (kg == q) ? xv : zerob;   // isolate i = i0+t4*4+q
                f32x4 uh[NJ];
#pragma unroll
                for (int j = 0; j < NJ; ++j)
                    uh[j] = __builtin_amdgcn_mfma_f32_16x16x32_bf16(afull[j], bq, zero, 0, 0, 0);

                // per-lane partial dots over this lane's 4 d's (f32)
                float bd[NJ];
#pragma unroll
                for (int j = 0; j < NJ; ++j)
                    bd[j] = uh[j][0] * vs[j][0] + uh[j][1] * vs[j][1]
                          + uh[j][2] * vs[j][2] + uh[j][3] * vs[j][3];

                // fp16x2-packed butterfly over the 4 d-quad lane groups:
                // 10 shfl + 10 pk_add.
                h16x2 pk[5];
#pragma unroll
                for (int jp = 0; jp < 5; ++jp)
                    pk[jp] = __builtin_amdgcn_cvt_pkrtz(bd[2 * jp], bd[2 * jp + 1]);
#pragma unroll
                for (int jp = 0; jp < 5; ++jp) {
                    float f = __shfl_xor(__builtin_bit_cast(float, pk[jp]), 16, 64);
                    pk[jp] = pk[jp] + __builtin_bit_cast(h16x2, f);
                }
#pragma unroll
                for (int jp = 0; jp < 5; ++jp) {
                    float f = __shfl_xor(__builtin_bit_cast(float, pk[jp]), 32, 64);
                    pk[jp] = pk[jp] + __builtin_bit_cast(h16x2, f);
                }

                // softmax over j, no max-subtract (|logit| <= ~3, exp safe)
                float e[NJ];
#pragma unroll
                for (int jp = 0; jp < 5; ++jp) {
                    e[2 * jp]     = __expf((float)pk[jp][0]);
                    e[2 * jp + 1] = __expf((float)pk[jp][1]);
                }
                float Z = ((e[0] + e[1]) + (e[2] + e[3]))
                        + ((e[4] + e[5]) + (e[6] + e[7])) + (e[8] + e[9]);
                const float rZ = 1.f / Z;
#pragma unroll
                for (int j = 0; j < NJ; ++j) {
                    const float c = e[j] * rZ;
                    sacc[j] += c * uh[j];
                }
            }
        }
    }

    // epilogue: sacc -> bf16 LDS bounce -> dense contiguous bf16 partials
    __syncthreads();
    unsigned short* s16 = (unsigned short*)smem;   // [64][168]
#pragma unroll
    for (int j = 0; j < NJ; ++j) {
        ushort4 o;
        o.x = f2bf(sacc[j][0]); o.y = f2bf(sacc[j][1]);
        o.z = f2bf(sacc[j][2]); o.w = f2bf(sacc[j][3]);
        *(ushort4*)(s16 + brow * 168 + j * 16 + kg * 4) = o;
    }
    __syncthreads();
    unsigned short* pp = part + ((size_t)ig * NB + b0) * 160;
#pragma unroll
    for (int r = 0; r < 5; ++r) {
        int idx = tid + r * 256;                 // 1280 ushort8 chunks = 64x160
        int row = idx / 20, ch = idx - row * 20;
        *(u16x8*)(pp + idx * 8) = *(const u16x8*)(s16 + row * 168 + ch * 8);
    }
}

// Sum 144 bf16 ig-partials, scale, squash over d (16-lane shfl), update vsum/out.
__global__ __launch_bounds__(256)
void squash_reduce(const unsigned short* __restrict__ part,
                   float* __restrict__ vsum_g, float* __restrict__ out,
                   float alpha, int mode)
{
    const int t = blockIdx.x * 256 + threadIdx.x;   // < 81920 = b*160 + j*16 + d
    const unsigned short* p = part + t;
    float a0 = 0.f, a1 = 0.f, a2 = 0.f, a3 = 0.f;
#pragma unroll 4
    for (int ig = 0; ig < NIGB; ig += 4) {
        a0 += bf2f(p[(size_t)ig * 81920]);
        a1 += bf2f(p[(size_t)(ig + 1) * 81920]);
        a2 += bf2f(p[(size_t)(ig + 2) * 81920]);
        a3 += bf2f(p[(size_t)(ig + 3) * 81920]);
    }
    const float s = ((a0 + a1) + (a2 + a3)) * alpha;

    float sq = s * s;
    sq += __shfl_xor(sq, 1, 64);
    sq += __shfl_xor(sq, 2, 64);
    sq += __shfl_xor(sq, 4, 64);
    sq += __shfl_xor(sq, 8, 64);
    const float sc = sq / ((1.f + sq) * sqrtf(sq + EPS_));
    const float v  = sc * s;

    if (mode == 0)      vsum_g[t] = v;
    else if (mode == 1) vsum_g[t] += v;
    else                out[t] = v;
}

extern "C" void kernel_launch(void* const* d_in, const int* in_sizes, int n_in,
                              void* d_out, int out_size, void* d_ws, size_t ws_size,
                              hipStream_t stream)
{
    const float* inp = (const float*)d_in[0];
    const float* Wg  = (const float*)d_in[1];
    float* out = (float*)d_out;

    unsigned short* xbp  = (unsigned short*)d_ws;
    unsigned short* wbp  = xbp + XB_ELEMS;
    unsigned short* part = wbp + WB_ELEMS;                    // [144][512][160] bf16
    float* vsum = (float*)(part + (size_t)NIGB * NB * 160);   // [512][10][16] f32

    conv_bf16<<<(XQ + WQ + 255) / 256, 256, 0, stream>>>(inp, Wg, xbp, wbp);

    dim3 grid(8, NIGB);   // (8,144) = 1152 blocks
    // iter 0: c uniform 1/10 (folded into alpha); K=32 contracts 4 i's exactly
    caps_pass<0><<<grid, 256, 0, stream>>>(xbp, wbp, nullptr, part);
    squash_reduce<<<320, 256, 0, stream>>>(part, vsum, out, 0.1f, 0);
    // iter 1: logits = u_hat . v0
    caps_pass<1><<<grid, 256, 0, stream>>>(xbp, wbp, vsum, part);
    squash_reduce<<<320, 256, 0, stream>>>(part, vsum, out, 1.0f, 1);
    // iter 2: logits = u_hat . (v0+v1)
    caps_pass<1><<<grid, 256, 0, stream>>>(xbp, wbp, vsum, part);
    squash_reduce<<<320, 256, 0, stream>>>(part, vsum, out, 1.0f, 2);
}